// Round 1
// baseline (3339.602 us; speedup 1.0000x reference)
//
#include <hip/hip_runtime.h>
#include <math.h>

#define D_  768
#define B_  16
#define S_  1024
#define M_  16
#define SM_ 1040            // S + M
#define SCALE_ 0.036084392f // 1.0 / np.sqrt(768) (f32)

// ---------------------------------------------------------------------------
// Tiled fp32 GEMM: dst[row, e] = sum_d src[row, d] * W[e, d] + bias[e]
// Tile 64x64, K-chunks of 16, K-major LDS (stride 68 => 16B-aligned b128 reads,
// <=2-way bank aliasing). kvmap=1: row -> concat(x[b,0:1024], memory) stream.
// rows are exact multiples of 64 (16384 and 16640), D=768=48*16: no guards.
// ---------------------------------------------------------------------------
__launch_bounds__(256)
__global__ void proj_k(const float* __restrict__ src,
                       const float* __restrict__ xsrc,
                       const float* __restrict__ msrc,
                       const float* __restrict__ W,
                       const float* __restrict__ bias,
                       float* __restrict__ dst,
                       int kvmap)
{
    __shared__ __attribute__((aligned(16))) float As[16][68];
    __shared__ __attribute__((aligned(16))) float Bs[16][68];

    const int t   = threadIdx.x;
    const int tx  = t & 15;        // col group
    const int ty  = t >> 4;        // row group
    const int row0 = blockIdx.x * 64;
    const int col0 = blockIdx.y * 64;

    // loader mapping: 256 threads, each loads one float4 of A and one of B
    const int lrow = t >> 2;       // 0..63
    const int lkq  = t & 3;        // 0..3 (which float4 along K-chunk)

    const int grow = row0 + lrow;
    const float* arow;
    if (kvmap) {
        const int b  = grow / SM_;
        const int tt = grow - b * SM_;
        arow = (tt < S_) ? (xsrc + ((size_t)b * S_ + tt) * D_)
                         : (msrc + (size_t)(tt - S_) * D_);
    } else {
        arow = src + (size_t)grow * D_;
    }
    const float* brow = W + (size_t)(col0 + lrow) * D_;

    float acc[4][4] = {};

    for (int kt = 0; kt < D_; kt += 16) {
        const float4 a4 = *(const float4*)(arow + kt + lkq * 4);
        const float4 b4 = *(const float4*)(brow + kt + lkq * 4);
        As[lkq*4+0][lrow] = a4.x; As[lkq*4+1][lrow] = a4.y;
        As[lkq*4+2][lrow] = a4.z; As[lkq*4+3][lrow] = a4.w;
        Bs[lkq*4+0][lrow] = b4.x; Bs[lkq*4+1][lrow] = b4.y;
        Bs[lkq*4+2][lrow] = b4.z; Bs[lkq*4+3][lrow] = b4.w;
        __syncthreads();
        #pragma unroll
        for (int kk = 0; kk < 16; ++kk) {
            const float4 av = *(const float4*)&As[kk][ty*4];
            const float4 bv = *(const float4*)&Bs[kk][tx*4];
            const float a[4] = {av.x, av.y, av.z, av.w};
            const float b[4] = {bv.x, bv.y, bv.z, bv.w};
            #pragma unroll
            for (int i = 0; i < 4; ++i)
                #pragma unroll
                for (int j = 0; j < 4; ++j)
                    acc[i][j] += a[i] * b[j];
        }
        __syncthreads();
    }

    const float4 bb = *(const float4*)(bias + col0 + tx*4);
    #pragma unroll
    for (int i = 0; i < 4; ++i) {
        float4 o;
        o.x = acc[i][0] + bb.x; o.y = acc[i][1] + bb.y;
        o.z = acc[i][2] + bb.z; o.w = acc[i][3] + bb.w;
        *(float4*)(dst + (size_t)(row0 + ty*4 + i) * D_ + col0 + tx*4) = o;
    }
}

// ---------------------------------------------------------------------------
// Fused attention: one block = (batch b, 16 query rows). Full score row
// [16][1040] in LDS. Phase A: scores = q @ k^T * scale + mask (tiled, 64 kv
// cols at a time). Phase B: softmax in LDS. Phase C: hout = attn @ v (tiled,
// 64 d cols at a time). hout overwrites the q workspace (rows owned by block).
// ---------------------------------------------------------------------------
#define SCW 1044   // 1040 + 4 pad: row stride % 32 = 20 -> rows hit distinct banks

__launch_bounds__(256)
__global__ void attn_k(const float* __restrict__ q,
                       const float* __restrict__ kmat,
                       const float* __restrict__ vmat,
                       const float* __restrict__ mask,
                       float* __restrict__ hout)
{
    __shared__ __attribute__((aligned(16))) float sc[16][SCW];
    __shared__ __attribute__((aligned(16))) float Qs[16][20];
    __shared__ __attribute__((aligned(16))) float Ks[16][68]; // reused as Vs

    const int b  = blockIdx.y;
    const int q0 = blockIdx.x * 16;
    const int t  = threadIdx.x;
    const int tx = t & 15;
    const int ty = t >> 4;
    const int lrow = t >> 2;  // 0..63
    const int lkq  = t & 3;

    const float* qbase = q    + ((size_t)b * S_  + q0) * D_;
    const float* kbase = kmat + (size_t)b * SM_ * D_;
    const float* vbase = vmat + (size_t)b * SM_ * D_;

    // ---- Phase A: scores ----
    for (int ct = 0; ct < 17; ++ct) {
        float acc[4] = {0.f, 0.f, 0.f, 0.f};
        const int kvcol = ct*64 + lrow;
        const bool kvvalid = kvcol < SM_;
        const float* krow = kbase + (size_t)kvcol * D_;

        for (int kt = 0; kt < D_; kt += 16) {
            if (t < 64) {  // 16 q rows x 16 K
                const float4 a4 = *(const float4*)(qbase + (size_t)(t>>2)*D_ + kt + (t&3)*4);
                Qs[(t&3)*4+0][t>>2] = a4.x; Qs[(t&3)*4+1][t>>2] = a4.y;
                Qs[(t&3)*4+2][t>>2] = a4.z; Qs[(t&3)*4+3][t>>2] = a4.w;
            }
            float4 k4 = make_float4(0.f,0.f,0.f,0.f);
            if (kvvalid) k4 = *(const float4*)(krow + kt + lkq*4);
            Ks[lkq*4+0][lrow] = k4.x; Ks[lkq*4+1][lrow] = k4.y;
            Ks[lkq*4+2][lrow] = k4.z; Ks[lkq*4+3][lrow] = k4.w;
            __syncthreads();
            #pragma unroll
            for (int kk = 0; kk < 16; ++kk) {
                const float a = Qs[kk][ty];
                const float4 kv4 = *(const float4*)&Ks[kk][tx*4];
                acc[0] += a * kv4.x; acc[1] += a * kv4.y;
                acc[2] += a * kv4.z; acc[3] += a * kv4.w;
            }
            __syncthreads();
        }
        const int c0 = ct*64 + tx*4;
        if (c0 < SM_) {
            const float4 m4 = *(const float4*)(mask + (size_t)(q0 + ty) * SM_ + c0);
            sc[ty][c0+0] = acc[0]*SCALE_ + m4.x;
            sc[ty][c0+1] = acc[1]*SCALE_ + m4.y;
            sc[ty][c0+2] = acc[2]*SCALE_ + m4.z;
            sc[ty][c0+3] = acc[3]*SCALE_ + m4.w;
        }
    }
    __syncthreads();

    // ---- Phase B: softmax over each of the 16 rows (16 lanes per row) ----
    {
        const int r = ty;
        float m = -1e30f;
        for (int c = tx; c < SM_; c += 16) m = fmaxf(m, sc[r][c]);
        #pragma unroll
        for (int o = 8; o; o >>= 1) m = fmaxf(m, __shfl_xor(m, o, 16));
        float s = 0.f;
        for (int c = tx; c < SM_; c += 16) {
            const float e = __expf(sc[r][c] - m);
            sc[r][c] = e; s += e;
        }
        #pragma unroll
        for (int o = 8; o; o >>= 1) s += __shfl_xor(s, o, 16);
        const float inv = 1.f / s;
        for (int c = tx; c < SM_; c += 16) sc[r][c] *= inv;
    }
    __syncthreads();

    // ---- Phase C: hout = attn @ v ----
    for (int dt = 0; dt < 12; ++dt) {
        float acc[4] = {0.f, 0.f, 0.f, 0.f};
        for (int tc = 0; tc < 65; ++tc) {   // 1040 = 65 * 16 exactly
            const float4 v4 = *(const float4*)(vbase
                              + (size_t)(tc*16 + ty) * D_ + dt*64 + tx*4);
            __syncthreads();   // previous Vs users done
            *(float4*)&Ks[ty][tx*4] = v4;
            __syncthreads();
            #pragma unroll
            for (int kk = 0; kk < 16; ++kk) {
                const float p = sc[ty][tc*16 + kk];
                const float4 vv = *(const float4*)&Ks[kk][tx*4];
                acc[0] += p * vv.x; acc[1] += p * vv.y;
                acc[2] += p * vv.z; acc[3] += p * vv.w;
            }
        }
        float4 o4 = make_float4(acc[0], acc[1], acc[2], acc[3]);
        *(float4*)(hout + ((size_t)b * S_ + q0 + ty) * D_ + dt*64 + tx*4) = o4;
    }
}

// ---------------------------------------------------------------------------
extern "C" void kernel_launch(void* const* d_in, const int* in_sizes, int n_in,
                              void* d_out, int out_size, void* d_ws, size_t ws_size,
                              hipStream_t stream) {
    const float* x    = (const float*)d_in[0];
    const float* mask = (const float*)d_in[1];
    const float* mem  = (const float*)d_in[2];
    const float* wq   = (const float*)d_in[3];
    const float* bq   = (const float*)d_in[4];
    const float* wk   = (const float*)d_in[5];
    const float* bk   = (const float*)d_in[6];
    const float* wv   = (const float*)d_in[7];
    const float* bv   = (const float*)d_in[8];
    const float* wo   = (const float*)d_in[9];
    const float* bo   = (const float*)d_in[10];
    float* out = (float*)d_out;

    // workspace: q [16384*768] | k [16640*768] | v [16640*768]  (~145.5 MiB)
    float* qws = (float*)d_ws;
    float* kws = qws + (size_t)16384 * D_;
    float* vws = kws + (size_t)16640 * D_;

    const dim3 blk(256);
    // q = x @ wq^T + bq
    proj_k<<<dim3(256, 12), blk, 0, stream>>>(x, nullptr, nullptr, wq, bq, qws, 0);
    // k = concat(x, mem) @ wk^T + bk ; v likewise
    proj_k<<<dim3(260, 12), blk, 0, stream>>>(nullptr, x, mem, wk, bk, kws, 1);
    proj_k<<<dim3(260, 12), blk, 0, stream>>>(nullptr, x, mem, wv, bv, vws, 1);
    // fused scores -> softmax -> PV ; head_out overwrites qws
    attn_k<<<dim3(64, 16), blk, 0, stream>>>(qws, kws, vws, mask, qws);
    // out = head_out @ wo^T + bo
    proj_k<<<dim3(256, 12), blk, 0, stream>>>(qws, nullptr, nullptr, wo, bo, out, 0);
}

// Round 2
// 420.680 us; speedup vs baseline: 7.9386x; 7.9386x over previous
//
#include <hip/hip_runtime.h>
#include <math.h>
#include <stdint.h>

#define D_    768
#define B_    16
#define S_    1024
#define M_    16
#define SM_   1040           // S + M
#define SMP_  1088           // padded kv length (17*64) for PV K-loop
#define SCALE_ 0.036084392f  // 1/sqrt(768)

typedef __bf16 bf16;
typedef __attribute__((ext_vector_type(8))) __bf16 bf16x8;
typedef __attribute__((ext_vector_type(4))) __bf16 bf16x4;
typedef __attribute__((ext_vector_type(4))) float  f32x4;

// async global->LDS, 16B per lane; LDS dest = wave-uniform base + lane*16
#define GL16(gp, lp) __builtin_amdgcn_global_load_lds( \
    (const __attribute__((address_space(1))) void*)(gp), \
    (__attribute__((address_space(3))) void*)(lp), 16, 0, 0)

// ---------------------------------------------------------------------------
// NT GEMM, 128x128 tile, BK=64, bf16 MFMA 16x16x32, 4 waves (2x2), 4x4 frags.
// C[row, col] = sum_k A[row,k] * B[col,k]  (+bias[col])
// LDS layout: row-major [128][64] bf16, 16B chunks XOR-swizzled within each
// 128B row: position p holds chunk p ^ (row&7)  -> fragment ds_read_b128s
// spread uniformly over banks; staging stays lane-contiguous for
// global_load_lds (swizzle applied to the global source address).
// AMODE 0: A is bf16, staged via global_load_lds.
// AMODE 1: A is fp32 (x, or concat(x,mem) stream when kvmap=1), converted to
//          bf16 during staging via VGPR + ds_write_b128 (same swizzle).
// B is always bf16 (row = output col, k-contiguous), row index clamped to
// colsB-1 (scores GEMM last col tile); epilogue stores guarded col<colsB.
// ---------------------------------------------------------------------------
template<int AMODE, int OUTF32>
__launch_bounds__(256)
__global__ void gemm_k(const bf16*  __restrict__ Ab,
                       const float* __restrict__ Af,
                       const float* __restrict__ Mf,
                       int kvmap,
                       const bf16*  __restrict__ Bm,
                       const float* __restrict__ bias,
                       void* __restrict__ Cout,
                       int lda, int ldb, int ldc,
                       int K, int colsB,
                       long sA, long sB, long sC)
{
    __shared__ __attribute__((aligned(16))) bf16 As[128 * 64];
    __shared__ __attribute__((aligned(16))) bf16 Bs[128 * 64];

    const int t    = threadIdx.x;
    const int l    = t & 63;
    const int wv   = t >> 6;
    const int row0 = blockIdx.x * 128;
    const int col0 = blockIdx.y * 128;
    const int z    = blockIdx.z;

    // per-lane staging source pointers (fixed across K-loop)
    const bf16*  agb[4];
    const float* agf[4];
    const bf16*  bgb[4];
    int aw[4];
    #pragma unroll
    for (int i = 0; i < 4; ++i) {
        const int r = (wv * 4 + i) * 8 + (l >> 3);   // tile row 0..127
        const int c = (l & 7) ^ (r & 7);             // swizzled source chunk
        if (AMODE == 0) {
            agb[i] = Ab + (size_t)z * sA + (size_t)(row0 + r) * lda + c * 8;
        } else {
            const int grow = row0 + r;
            const float* base;
            if (kvmap) {
                const int b  = grow / SM_;
                const int tt = grow - b * SM_;
                base = (tt < S_) ? (Af + ((size_t)b * S_ + tt) * D_)
                                 : (Mf + (size_t)(tt - S_) * D_);
            } else {
                base = Af + (size_t)grow * lda;
            }
            agf[i] = base + c * 8;
            aw[i]  = r * 64 + (l & 7) * 8;           // LDS dest (elements)
        }
        int bcol = col0 + r;
        if (bcol > colsB - 1) bcol = colsB - 1;      // clamp (scores last tile)
        bgb[i] = Bm + (size_t)z * sB + (size_t)bcol * ldb + c * 8;
    }

    f32x4 acc[4][4];
    #pragma unroll
    for (int i = 0; i < 4; ++i)
        #pragma unroll
        for (int j = 0; j < 4; ++j)
            acc[i][j] = (f32x4){0.f, 0.f, 0.f, 0.f};

    const int wr0 = (wv & 1) * 64;
    const int wc0 = (wv >> 1) * 64;
    const int lq  = l >> 4;
    const int lm  = l & 15;

    for (int kt = 0; kt < K; kt += 64) {
        __syncthreads();   // previous tile's fragment reads done
        if (AMODE == 0) {
            #pragma unroll
            for (int i = 0; i < 4; ++i)
                GL16(agb[i] + kt, &As[(wv * 4 + i) * 512]);
        } else {
            #pragma unroll
            for (int i = 0; i < 4; ++i) {
                const float4 f0 = *(const float4*)(agf[i] + kt);
                const float4 f1 = *(const float4*)(agf[i] + kt + 4);
                bf16x8 v;
                v[0] = (bf16)f0.x; v[1] = (bf16)f0.y;
                v[2] = (bf16)f0.z; v[3] = (bf16)f0.w;
                v[4] = (bf16)f1.x; v[5] = (bf16)f1.y;
                v[6] = (bf16)f1.z; v[7] = (bf16)f1.w;
                *(bf16x8*)&As[aw[i]] = v;
            }
        }
        #pragma unroll
        for (int i = 0; i < 4; ++i)
            GL16(bgb[i] + kt, &Bs[(wv * 4 + i) * 512]);
        __syncthreads();   // staging visible (vmcnt+lgkm drained at barrier)

        #pragma unroll
        for (int ks = 0; ks < 2; ++ks) {
            bf16x8 af[4], bfr[4];
            #pragma unroll
            for (int i = 0; i < 4; ++i) {
                const int rowA = wr0 + i * 16 + lm;
                const int p = (ks * 4 + lq) ^ (rowA & 7);
                af[i] = *(const bf16x8*)&As[rowA * 64 + p * 8];
            }
            #pragma unroll
            for (int j = 0; j < 4; ++j) {
                const int rowB = wc0 + j * 16 + lm;
                const int p = (ks * 4 + lq) ^ (rowB & 7);
                bfr[j] = *(const bf16x8*)&Bs[rowB * 64 + p * 8];
            }
            #pragma unroll
            for (int i = 0; i < 4; ++i)
                #pragma unroll
                for (int j = 0; j < 4; ++j)
                    acc[i][j] = __builtin_amdgcn_mfma_f32_16x16x32_bf16(
                        af[i], bfr[j], acc[i][j], 0, 0, 0);
        }
    }

    // epilogue: C/D layout col=lane&15, row=quad*4+reg (m89/m91 verified)
    #pragma unroll
    for (int j = 0; j < 4; ++j) {
        const int gcol = col0 + wc0 + j * 16 + lm;
        if (gcol < colsB) {
            const float bv = bias ? bias[gcol] : 0.f;
            #pragma unroll
            for (int i = 0; i < 4; ++i) {
                #pragma unroll
                for (int r = 0; r < 4; ++r) {
                    const int grow = row0 + wr0 + i * 16 + lq * 4 + r;
                    const float val = acc[i][j][r] + bv;
                    const size_t idx = (size_t)z * sC + (size_t)grow * ldc + gcol;
                    if (OUTF32) ((float*)Cout)[idx] = val;
                    else        ((bf16*)Cout)[idx]  = (bf16)val;
                }
            }
        }
    }
}

// ---------------------------------------------------------------------------
// V [b, t, e] (bf16, t<1040) -> Vt [b, e, t] (bf16, t padded to 1088, pad=0)
// 64x64 tiles via LDS, both global sides 16B coalesced.
// ---------------------------------------------------------------------------
__launch_bounds__(256)
__global__ void transp_k(const bf16* __restrict__ V, bf16* __restrict__ Vt)
{
    __shared__ bf16 Ts[64][72];
    const int t   = threadIdx.x;
    const int tt0 = blockIdx.x * 64;   // t tile (17 tiles -> covers 0..1087)
    const int e0  = blockIdx.y * 64;   // e tile (12)
    const int b   = blockIdx.z;

    const int rr = t >> 3;             // 0..31
    const int c8 = (t & 7) * 8;

    #pragma unroll
    for (int it = 0; it < 2; ++it) {
        const int r = rr + it * 32;
        const int trow = tt0 + r;
        bf16x8 v;
        #pragma unroll
        for (int k = 0; k < 8; ++k) v[k] = (bf16)0.f;
        if (trow < SM_)
            v = *(const bf16x8*)(V + ((size_t)b * SM_ + trow) * D_ + e0 + c8);
        *(bf16x8*)&Ts[r][c8] = v;
    }
    __syncthreads();
    #pragma unroll
    for (int it = 0; it < 2; ++it) {
        const int e = rr + it * 32;
        bf16x8 v;
        #pragma unroll
        for (int k = 0; k < 8; ++k) v[k] = Ts[c8 + k][e];
        *(bf16x8*)(Vt + ((size_t)b * D_ + e0 + e) * SMP_ + tt0 + c8) = v;
    }
}

// ---------------------------------------------------------------------------
__global__ void castw_k(const float* __restrict__ in, bf16* __restrict__ out,
                        int n4)
{
    const int i = blockIdx.x * blockDim.x + threadIdx.x;
    if (i < n4) {
        const float4 f = ((const float4*)in)[i];
        bf16x4 v;
        v[0] = (bf16)f.x; v[1] = (bf16)f.y; v[2] = (bf16)f.z; v[3] = (bf16)f.w;
        ((bf16x4*)out)[i] = v;
    }
}

// ---------------------------------------------------------------------------
// In-place softmax over P rows (bf16, stride 1088): reads raw scores,
// applies SCALE + mask, writes normalized probs; zero-fills cols 1040..1087.
// 4 rows/block, 64 lanes/row.
// ---------------------------------------------------------------------------
__launch_bounds__(256)
__global__ void softmax_k(bf16* __restrict__ P, const float* __restrict__ mask)
{
    const int t   = threadIdx.x;
    const int row = blockIdx.x * 4 + (t >> 6);
    const int l   = t & 63;
    const int s   = row & 1023;
    bf16* prow = P + (size_t)row * SMP_;
    const float* mrow = mask + (size_t)s * SM_;

    float v[17];
    float m = -1e30f;
    #pragma unroll
    for (int it = 0; it < 17; ++it) {
        const int idx = l + it * 64;
        float x = -1e30f;
        if (idx < SM_) x = (float)prow[idx] * SCALE_ + mrow[idx];
        v[it] = x;
        m = fmaxf(m, x);
    }
    #pragma unroll
    for (int o = 32; o; o >>= 1) m = fmaxf(m, __shfl_xor(m, o));
    float sum = 0.f;
    #pragma unroll
    for (int it = 0; it < 17; ++it) {
        const int idx = l + it * 64;
        float e = 0.f;
        if (idx < SM_) e = __expf(v[it] - m);
        v[it] = e; sum += e;
    }
    #pragma unroll
    for (int o = 32; o; o >>= 1) sum += __shfl_xor(sum, o);
    const float inv = 1.f / sum;
    #pragma unroll
    for (int it = 0; it < 17; ++it) {
        const int idx = l + it * 64;
        if (idx < SMP_) prow[idx] = (bf16)(v[it] * inv);  // pad lanes write 0
    }
}

// ---------------------------------------------------------------------------
extern "C" void kernel_launch(void* const* d_in, const int* in_sizes, int n_in,
                              void* d_out, int out_size, void* d_ws, size_t ws_size,
                              hipStream_t stream) {
    const float* x    = (const float*)d_in[0];
    const float* mask = (const float*)d_in[1];
    const float* mem  = (const float*)d_in[2];
    const float* wq   = (const float*)d_in[3];
    const float* bq   = (const float*)d_in[4];
    const float* wk   = (const float*)d_in[5];
    const float* bk   = (const float*)d_in[6];
    const float* wv   = (const float*)d_in[7];
    const float* bv   = (const float*)d_in[8];
    const float* wo   = (const float*)d_in[9];
    const float* bo   = (const float*)d_in[10];

    // ws layout (bf16 elements), total ~136.8 MiB (< 145.5 MiB proven in R1)
    bf16* w = (bf16*)d_ws;
    const size_t NW  = (size_t)D_ * D_;          //   589824
    const size_t NQ  = (size_t)B_ * S_ * D_;     // 12582912
    const size_t NKV = (size_t)B_ * SM_ * D_;    // 12779520
    const size_t NVT = (size_t)B_ * D_ * SMP_;   // 13369344
    bf16* wqb = w;              bf16* wkb = wqb + NW;
    bf16* wvb = wkb + NW;       bf16* wob = wvb + NW;
    bf16* qb  = wob + NW;       // also reused as head_out (h)
    bf16* kb  = qb  + NQ;
    bf16* vb  = kb  + NKV;
    bf16* vtb = vb  + NKV;
    bf16* Pb  = vtb + NVT;      // [B,1024,1088] scores -> probs (in-place)

    const int n4w = (int)(NW / 4);
    castw_k<<<576, 256, 0, stream>>>(wq, wqb, n4w);
    castw_k<<<576, 256, 0, stream>>>(wk, wkb, n4w);
    castw_k<<<576, 256, 0, stream>>>(wv, wvb, n4w);
    castw_k<<<576, 256, 0, stream>>>(wo, wob, n4w);

    // Q = x @ wq^T + bq               [16384 x 768]
    gemm_k<1, 0><<<dim3(128, 6, 1), 256, 0, stream>>>(
        nullptr, x, nullptr, 0, wqb, bq, qb, D_, D_, D_, D_, D_, 0, 0, 0);
    // K/V = concat(x, mem) @ w^T + b  [16640 x 768]
    gemm_k<1, 0><<<dim3(130, 6, 1), 256, 0, stream>>>(
        nullptr, x, mem, 1, wkb, bk, kb, D_, D_, D_, D_, D_, 0, 0, 0);
    gemm_k<1, 0><<<dim3(130, 6, 1), 256, 0, stream>>>(
        nullptr, x, mem, 1, wvb, bv, vb, D_, D_, D_, D_, D_, 0, 0, 0);
    // Vt[b,e,t] with zero pad t in [1040,1088)
    transp_k<<<dim3(17, 12, 16), 256, 0, stream>>>(vb, vtb);
    // raw scores = q @ k^T  (bf16, per batch; SCALE+mask applied in softmax)
    gemm_k<0, 0><<<dim3(8, 9, 16), 256, 0, stream>>>(
        qb, nullptr, nullptr, 0, kb, nullptr, Pb,
        D_, D_, SMP_, D_, SM_,
        (long)S_ * D_, (long)SM_ * D_, (long)S_ * SMP_);
    softmax_k<<<(B_ * S_) / 4, 256, 0, stream>>>(Pb, mask);
    // head_out = P @ V  (K=1088, zero pad contributes 0) -> reuse qb
    gemm_k<0, 0><<<dim3(8, 6, 16), 256, 0, stream>>>(
        Pb, nullptr, nullptr, 0, vtb, nullptr, qb,
        SMP_, SMP_, D_, SMP_, D_,
        (long)S_ * SMP_, (long)D_ * SMP_, (long)S_ * D_);
    // out = head_out @ wo^T + bo  (fp32)
    gemm_k<0, 1><<<dim3(128, 6, 1), 256, 0, stream>>>(
        qb, nullptr, nullptr, 0, wob, bo, d_out, D_, D_, D_, D_, D_, 0, 0, 0);
}

// Round 3
// 385.725 us; speedup vs baseline: 8.6580x; 1.0906x over previous
//
#include <hip/hip_runtime.h>
#include <math.h>
#include <stdint.h>

#define D_    768
#define B_    16
#define S_    1024
#define M_    16
#define SM_   1040           // S + M
#define SMP_  1088           // padded kv length (17*64) for PV K-loop
#define SCALE_ 0.036084392f  // 1/sqrt(768)

typedef __bf16 bf16;
typedef __attribute__((ext_vector_type(8))) __bf16 bf16x8;
typedef __attribute__((ext_vector_type(4))) __bf16 bf16x4;
typedef __attribute__((ext_vector_type(4))) float  f32x4;

// async global->LDS, 16B per lane; LDS dest = wave-uniform base + lane*16
#define GL16(gp, lp) __builtin_amdgcn_global_load_lds( \
    (const __attribute__((address_space(1))) void*)(gp), \
    (__attribute__((address_space(3))) void*)(lp), 16, 0, 0)

// ---------------------------------------------------------------------------
// NT GEMM, 128x128 tile, BK=64, bf16 MFMA 16x16x32, 4 waves (2x2), 4x4 frags.
// C[row, col] = sum_k A[row,k] * B[col,k]  (+bias[col])
// Both operands staged via global_load_lds width=16. LDS: row-major [128][64]
// bf16, 16B chunks XOR-swizzled within each 128B row (position p holds global
// chunk p ^ (row&7)) so fragment ds_read_b128s are bank-uniform while staging
// stays lane-contiguous (swizzle applied on the global source address).
// B row index clamped to colsB-1 (scores last col tile); stores col-guarded.
// OUTMODE 0: bf16 row-major.  1: fp32 row-major.
// OUTMODE 2: bf16 transposed with batch decode (V -> Vt[b, e, t], ldc=SMP_):
//            global row = b*1040 + t; 4-row acc groups are 4-aligned and 1040
//            is a multiple of 4, so a group never spans a batch boundary ->
//            bf16x4 stores.
// ---------------------------------------------------------------------------
template<int OUTMODE>
__launch_bounds__(256)
__global__ void gemm_k(const bf16*  __restrict__ Am,
                       const bf16*  __restrict__ Bm,
                       const float* __restrict__ bias,
                       void* __restrict__ Cout,
                       int lda, int ldb, int ldc,
                       int K, int colsB,
                       long sA, long sB, long sC)
{
    __shared__ __attribute__((aligned(16))) bf16 As[128 * 64];
    __shared__ __attribute__((aligned(16))) bf16 Bs[128 * 64];

    const int t    = threadIdx.x;
    const int l    = t & 63;
    const int wv   = t >> 6;
    const int row0 = blockIdx.x * 128;
    const int col0 = blockIdx.y * 128;
    const int z    = blockIdx.z;

    const bf16* agb[4];
    const bf16* bgb[4];
    #pragma unroll
    for (int i = 0; i < 4; ++i) {
        const int r = (wv * 4 + i) * 8 + (l >> 3);   // tile row 0..127
        const int c = (l & 7) ^ (r & 7);             // swizzled source chunk
        agb[i] = Am + (size_t)z * sA + (size_t)(row0 + r) * lda + c * 8;
        int bcol = col0 + r;
        if (bcol > colsB - 1) bcol = colsB - 1;
        bgb[i] = Bm + (size_t)z * sB + (size_t)bcol * ldb + c * 8;
    }

    f32x4 acc[4][4];
    #pragma unroll
    for (int i = 0; i < 4; ++i)
        #pragma unroll
        for (int j = 0; j < 4; ++j)
            acc[i][j] = (f32x4){0.f, 0.f, 0.f, 0.f};

    const int wr0 = (wv & 1) * 64;
    const int wc0 = (wv >> 1) * 64;
    const int lq  = l >> 4;
    const int lm  = l & 15;

    for (int kt = 0; kt < K; kt += 64) {
        __syncthreads();   // previous tile's fragment reads done
        #pragma unroll
        for (int i = 0; i < 4; ++i)
            GL16(agb[i] + kt, &As[(wv * 4 + i) * 512]);
        #pragma unroll
        for (int i = 0; i < 4; ++i)
            GL16(bgb[i] + kt, &Bs[(wv * 4 + i) * 512]);
        __syncthreads();   // staging visible

        #pragma unroll
        for (int ks = 0; ks < 2; ++ks) {
            bf16x8 af[4], bfr[4];
            #pragma unroll
            for (int i = 0; i < 4; ++i) {
                const int rowA = wr0 + i * 16 + lm;
                const int p = (ks * 4 + lq) ^ (rowA & 7);
                af[i] = *(const bf16x8*)&As[rowA * 64 + p * 8];
            }
            #pragma unroll
            for (int j = 0; j < 4; ++j) {
                const int rowB = wc0 + j * 16 + lm;
                const int p = (ks * 4 + lq) ^ (rowB & 7);
                bfr[j] = *(const bf16x8*)&Bs[rowB * 64 + p * 8];
            }
            #pragma unroll
            for (int i = 0; i < 4; ++i)
                #pragma unroll
                for (int j = 0; j < 4; ++j)
                    acc[i][j] = __builtin_amdgcn_mfma_f32_16x16x32_bf16(
                        af[i], bfr[j], acc[i][j], 0, 0, 0);
        }
    }

    // epilogue: C/D layout col=lane&15, row=quad*4+reg (m89/m91 verified)
    #pragma unroll
    for (int j = 0; j < 4; ++j) {
        const int gcol = col0 + wc0 + j * 16 + lm;
        if (gcol < colsB) {
            const float bv = bias ? bias[gcol] : 0.f;
            #pragma unroll
            for (int i = 0; i < 4; ++i) {
                const int t0 = row0 + wr0 + i * 16 + lq * 4;  // 4-aligned
                if (OUTMODE == 2) {
                    const int b  = t0 / SM_;
                    const int tt = t0 - b * SM_;
                    bf16x4 o;
                    #pragma unroll
                    for (int r = 0; r < 4; ++r) o[r] = (bf16)(acc[i][j][r] + bv);
                    *(bf16x4*)((bf16*)Cout +
                        ((size_t)b * D_ + gcol) * SMP_ + tt) = o;
                } else {
                    #pragma unroll
                    for (int r = 0; r < 4; ++r) {
                        const float val = acc[i][j][r] + bv;
                        const size_t idx = (size_t)z * sC
                                         + (size_t)(t0 + r) * ldc + gcol;
                        if (OUTMODE == 1) ((float*)Cout)[idx] = val;
                        else              ((bf16*)Cout)[idx]  = (bf16)val;
                    }
                }
            }
        }
    }
}

// ---------------------------------------------------------------------------
// Batched weight cast: 4 weight matrices [768x768] fp32 -> bf16, y = which.
// ---------------------------------------------------------------------------
__global__ void castw4_k(const float* __restrict__ w0, const float* __restrict__ w1,
                         const float* __restrict__ w2, const float* __restrict__ w3,
                         bf16* __restrict__ o0, bf16* __restrict__ o1,
                         bf16* __restrict__ o2, bf16* __restrict__ o3)
{
    const float* in;
    bf16* out;
    switch (blockIdx.y) {
        case 0: in = w0; out = o0; break;
        case 1: in = w1; out = o1; break;
        case 2: in = w2; out = o2; break;
        default: in = w3; out = o3; break;
    }
    const int i = blockIdx.x * blockDim.x + threadIdx.x;   // float4 chunks
    const float4 f = ((const float4*)in)[i];
    bf16x4 v;
    v[0] = (bf16)f.x; v[1] = (bf16)f.y; v[2] = (bf16)f.z; v[3] = (bf16)f.w;
    ((bf16x4*)out)[i] = v;
}

// ---------------------------------------------------------------------------
// cstream[b*1040 + t][e] = bf16( t<1024 ? x[b,t,e] : mem[t-1024,e] )
// one bf16x8 chunk per thread; 768/8 = 96 chunks per row.
// ---------------------------------------------------------------------------
__global__ void castx_k(const float* __restrict__ x, const float* __restrict__ mem,
                        bf16* __restrict__ cs)
{
    const int i = blockIdx.x * blockDim.x + threadIdx.x;  // 0 .. 16640*96-1
    const int row = i / 96;
    const int c8  = (i - row * 96) * 8;
    const int b   = row / SM_;
    const int tt  = row - b * SM_;
    const float* src = (tt < S_) ? (x + ((size_t)b * S_ + tt) * D_ + c8)
                                 : (mem + (size_t)(tt - S_) * D_ + c8);
    const float4 f0 = *(const float4*)src;
    const float4 f1 = *(const float4*)(src + 4);
    bf16x8 v;
    v[0] = (bf16)f0.x; v[1] = (bf16)f0.y; v[2] = (bf16)f0.z; v[3] = (bf16)f0.w;
    v[4] = (bf16)f1.x; v[5] = (bf16)f1.y; v[6] = (bf16)f1.z; v[7] = (bf16)f1.w;
    *(bf16x8*)(cs + (size_t)row * D_ + c8) = v;
}

// ---------------------------------------------------------------------------
// zero the Vt pad region t in [1040, 1088) for all (b, e) rows
// ---------------------------------------------------------------------------
__global__ void padz_k(bf16* __restrict__ vt)
{
    const int i  = blockIdx.x * blockDim.x + threadIdx.x;  // 0 .. 16*768*6-1
    const int be = i / 6;
    const int ch = i - be * 6;
    bf16x8 z;
    #pragma unroll
    for (int k = 0; k < 8; ++k) z[k] = (bf16)0.f;
    *(bf16x8*)(vt + (size_t)be * SMP_ + SM_ + ch * 8) = z;
}

// ---------------------------------------------------------------------------
// In-place softmax over P rows (bf16, stride 1088): reads raw scores,
// applies SCALE + mask, writes normalized probs; zero-fills pad cols.
// ---------------------------------------------------------------------------
__launch_bounds__(256)
__global__ void softmax_k(bf16* __restrict__ P, const float* __restrict__ mask)
{
    const int t   = threadIdx.x;
    const int row = blockIdx.x * 4 + (t >> 6);
    const int l   = t & 63;
    const int s   = row & 1023;
    bf16* prow = P + (size_t)row * SMP_;
    const float* mrow = mask + (size_t)s * SM_;

    float v[17];
    float m = -1e30f;
    #pragma unroll
    for (int it = 0; it < 17; ++it) {
        const int idx = l + it * 64;
        float x = -1e30f;
        if (idx < SM_) x = (float)prow[idx] * SCALE_ + mrow[idx];
        v[it] = x;
        m = fmaxf(m, x);
    }
    #pragma unroll
    for (int o = 32; o; o >>= 1) m = fmaxf(m, __shfl_xor(m, o));
    float sum = 0.f;
    #pragma unroll
    for (int it = 0; it < 17; ++it) {
        const int idx = l + it * 64;
        float e = 0.f;
        if (idx < SM_) e = __expf(v[it] - m);
        v[it] = e; sum += e;
    }
    #pragma unroll
    for (int o = 32; o; o >>= 1) sum += __shfl_xor(sum, o);
    const float inv = 1.f / sum;
    #pragma unroll
    for (int it = 0; it < 17; ++it) {
        const int idx = l + it * 64;
        if (idx < SMP_) prow[idx] = (bf16)(v[it] * inv);  // pad lanes write 0
    }
}

// ---------------------------------------------------------------------------
extern "C" void kernel_launch(void* const* d_in, const int* in_sizes, int n_in,
                              void* d_out, int out_size, void* d_ws, size_t ws_size,
                              hipStream_t stream) {
    const float* x    = (const float*)d_in[0];
    const float* mask = (const float*)d_in[1];
    const float* mem  = (const float*)d_in[2];
    const float* wq   = (const float*)d_in[3];
    const float* bq   = (const float*)d_in[4];
    const float* wk   = (const float*)d_in[5];
    const float* bk   = (const float*)d_in[6];
    const float* wv   = (const float*)d_in[7];
    const float* bv   = (const float*)d_in[8];
    const float* wo   = (const float*)d_in[9];
    const float* bo   = (const float*)d_in[10];

    // ws layout (bf16), total ~143.4 MB (< 145.5 MiB proven in R1)
    bf16* w = (bf16*)d_ws;
    const size_t NW  = (size_t)D_ * D_;          //   589824
    const size_t NCS = (size_t)B_ * SM_ * D_;    // 12779520 (cstream / head_out)
    const size_t NQ  = (size_t)B_ * S_ * D_;     // 12582912
    const size_t NKV = (size_t)B_ * SM_ * D_;    // 12779520
    const size_t NVT = (size_t)B_ * D_ * SMP_;   // 13369344
    bf16* wqb = w;              bf16* wkb = wqb + NW;
    bf16* wvb = wkb + NW;       bf16* wob = wvb + NW;
    bf16* cs  = wob + NW;       // concat(x, mem) bf16; reused as head_out
    bf16* qb  = cs  + NCS;
    bf16* kb  = qb  + NQ;
    bf16* vtb = kb  + NKV;
    bf16* Pb  = vtb + NVT;      // [B,1024,1088] scores -> probs (in-place)

    castw4_k<<<dim3(576, 4), 256, 0, stream>>>(wq, wk, wv, wo, wqb, wkb, wvb, wob);
    castx_k<<<6240, 256, 0, stream>>>(x, mem, cs);

    // Q = x @ wq^T + bq  (z-batched over cstream segments)  -> qb [B,1024,768]
    gemm_k<0><<<dim3(8, 6, 16), 256, 0, stream>>>(
        cs, wqb, bq, qb, D_, D_, D_, D_, D_,
        (long)SM_ * D_, 0, (long)S_ * D_);
    // K = cstream @ wk^T + bk  -> kb [16640, 768]
    gemm_k<0><<<dim3(130, 6, 1), 256, 0, stream>>>(
        cs, wkb, bk, kb, D_, D_, D_, D_, D_, 0, 0, 0);
    // V = cstream @ wv^T + bv, written transposed -> vtb [B, 768, 1088]
    gemm_k<2><<<dim3(130, 6, 1), 256, 0, stream>>>(
        cs, wvb, bv, vtb, D_, D_, SMP_, D_, D_, 0, 0, 0);
    padz_k<<<288, 256, 0, stream>>>(vtb);

    // raw scores = q @ k^T (per batch; SCALE+mask applied in softmax)
    gemm_k<0><<<dim3(8, 9, 16), 256, 0, stream>>>(
        qb, kb, nullptr, Pb, D_, D_, SMP_, D_, SM_,
        (long)S_ * D_, (long)SM_ * D_, (long)S_ * SMP_);
    softmax_k<<<(B_ * S_) / 4, 256, 0, stream>>>(Pb, mask);

    // head_out = P @ V  (K=1088, pad contributes 0) -> cs (dead) reused
    gemm_k<0><<<dim3(8, 6, 16), 256, 0, stream>>>(
        Pb, vtb, nullptr, cs, SMP_, SMP_, D_, SMP_, D_,
        (long)S_ * SMP_, (long)D_ * SMP_, (long)S_ * D_);
    // out = head_out @ wo^T + bo  (fp32)
    gemm_k<1><<<dim3(128, 6, 1), 256, 0, stream>>>(
        cs, wob, bo, d_out, D_, D_, D_, D_, D_, 0, 0, 0);
}

// Round 4
// 346.405 us; speedup vs baseline: 9.6408x; 1.1135x over previous
//
#include <hip/hip_runtime.h>
#include <math.h>
#include <stdint.h>

#define D_    768
#define B_    16
#define S_    1024
#define M_    16
#define SM_   1040           // S + M
#define SMP_  1088           // padded kv length (17*64) for PV K-loop
#define SCALE_ 0.036084392f  // 1/sqrt(768)

typedef __bf16 bf16;
typedef __attribute__((ext_vector_type(8))) __bf16 bf16x8;
typedef __attribute__((ext_vector_type(4))) __bf16 bf16x4;
typedef __attribute__((ext_vector_type(4))) float  f32x4;

// async global->LDS, 16B per lane; LDS dest = wave-uniform base + lane*16
#define GL16(gp, lp) __builtin_amdgcn_global_load_lds( \
    (const __attribute__((address_space(1))) void*)(gp), \
    (__attribute__((address_space(3))) void*)(lp), 16, 0, 0)

// ---------------------------------------------------------------------------
// NT GEMM, 128x128 tile, BK=64, bf16 MFMA 16x16x32, 4 waves (2x2), 4x4 frags.
// C[row, col] = sum_k A[row,k] * B[col,k]  (+bias[col])
// global_load_lds width=16 staging; LDS [128][64] bf16 with 16B chunks
// XOR-swizzled within each 128B row (chunk p holds global chunk p^(row&7)).
//
// GM (grid mode):
//  0: row0=bx*128, col0=by*128, z=bz                       (generic 3D)
//  1: flat XCD-swizzled, scores shape (8 rowtiles x 9 coltiles x 16 z):
//     xcd=bid&7 owns batches 2*xcd, 2*xcd+1 -> per-XCD L2 keeps Q+K resident
//  2: flat XCD-swizzled, PV shape (8 x 6 x 16): same idea for P+Vt
//  3: row0=by*128, col0=bx*128, z=0 (col-tile-fast: consecutive blocks share
//     the A row-tile; B fully L2-resident)
//
// OUTMODE 0: bf16 row-major.  1: fp32 row-major.
// OUTMODE 3: fused QKV epilogue. B = [wq;wk;wv] (2304 rows). wsel=col0/768
//   (block-uniform; 768%128==0 so no straddle). A rows are cstream rows
//   (b*1040+t). Q (wsel 0): -> Cout[b,t,:] bf16, skip t>=1024. K (wsel 1):
//   -> C2 row-major bf16 [16640,768]. V (wsel 2): -> C3 transposed
//   Vt[b, e, t] (ldc 1088) via bf16x4 (4-row groups 4-aligned, 1040%4==0,
//   1024%4==0 -> never straddle a batch or the Q-valid boundary).
// ---------------------------------------------------------------------------
template<int OUTMODE, int GM>
__launch_bounds__(256)
__global__ void gemm_k(const bf16*  __restrict__ Am,
                       const bf16*  __restrict__ Bm,
                       const float* __restrict__ bias,
                       void* __restrict__ Cout,
                       void* __restrict__ C2,
                       void* __restrict__ C3,
                       int lda, int ldb, int ldc,
                       int K, int colsB,
                       long sA, long sB, long sC)
{
    __shared__ __attribute__((aligned(16))) bf16 As[128 * 64];
    __shared__ __attribute__((aligned(16))) bf16 Bs[128 * 64];

    const int t    = threadIdx.x;
    const int l    = t & 63;
    const int wv   = t >> 6;

    int row0, col0, z;
    if (GM == 0) {
        row0 = blockIdx.x * 128; col0 = blockIdx.y * 128; z = blockIdx.z;
    } else if (GM == 1) {
        const int bid = blockIdx.x;           // 1152 blocks
        const int xcd = bid & 7, s = bid >> 3;
        z = xcd * 2 + s / 72;
        const int r = s % 72;
        row0 = (r & 7) * 128; col0 = (r >> 3) * 128;
    } else if (GM == 2) {
        const int bid = blockIdx.x;           // 768 blocks
        const int xcd = bid & 7, s = bid >> 3;
        z = xcd * 2 + s / 48;
        const int r = s % 48;
        row0 = (r & 7) * 128; col0 = (r >> 3) * 128;
    } else {
        row0 = blockIdx.y * 128; col0 = blockIdx.x * 128; z = 0;
    }

    const bf16* agb[4];
    const bf16* bgb[4];
    #pragma unroll
    for (int i = 0; i < 4; ++i) {
        const int r = (wv * 4 + i) * 8 + (l >> 3);   // tile row 0..127
        const int c = (l & 7) ^ (r & 7);             // swizzled source chunk
        agb[i] = Am + (size_t)z * sA + (size_t)(row0 + r) * lda + c * 8;
        int bcol = col0 + r;
        if (bcol > colsB - 1) bcol = colsB - 1;
        bgb[i] = Bm + (size_t)z * sB + (size_t)bcol * ldb + c * 8;
    }

    f32x4 acc[4][4];
    #pragma unroll
    for (int i = 0; i < 4; ++i)
        #pragma unroll
        for (int j = 0; j < 4; ++j)
            acc[i][j] = (f32x4){0.f, 0.f, 0.f, 0.f};

    const int wr0 = (wv & 1) * 64;
    const int wc0 = (wv >> 1) * 64;
    const int lq  = l >> 4;
    const int lm  = l & 15;

    for (int kt = 0; kt < K; kt += 64) {
        __syncthreads();   // previous tile's fragment reads done
        #pragma unroll
        for (int i = 0; i < 4; ++i)
            GL16(agb[i] + kt, &As[(wv * 4 + i) * 512]);
        #pragma unroll
        for (int i = 0; i < 4; ++i)
            GL16(bgb[i] + kt, &Bs[(wv * 4 + i) * 512]);
        __syncthreads();   // staging visible

        #pragma unroll
        for (int ks = 0; ks < 2; ++ks) {
            bf16x8 af[4], bfr[4];
            #pragma unroll
            for (int i = 0; i < 4; ++i) {
                const int rowA = wr0 + i * 16 + lm;
                const int p = (ks * 4 + lq) ^ (rowA & 7);
                af[i] = *(const bf16x8*)&As[rowA * 64 + p * 8];
            }
            #pragma unroll
            for (int j = 0; j < 4; ++j) {
                const int rowB = wc0 + j * 16 + lm;
                const int p = (ks * 4 + lq) ^ (rowB & 7);
                bfr[j] = *(const bf16x8*)&Bs[rowB * 64 + p * 8];
            }
            #pragma unroll
            for (int i = 0; i < 4; ++i)
                #pragma unroll
                for (int j = 0; j < 4; ++j)
                    acc[i][j] = __builtin_amdgcn_mfma_f32_16x16x32_bf16(
                        af[i], bfr[j], acc[i][j], 0, 0, 0);
        }
    }

    // epilogue: C/D layout col=lane&15, row=quad*4+reg (m89/m91 verified)
    const int wsel = (OUTMODE == 3) ? (col0 / 768) : 0;
    #pragma unroll
    for (int j = 0; j < 4; ++j) {
        const int gcol = col0 + wc0 + j * 16 + lm;
        if (gcol < colsB) {
            const float bv = bias ? bias[gcol] : 0.f;
            #pragma unroll
            for (int i = 0; i < 4; ++i) {
                const int t0 = row0 + wr0 + i * 16 + lq * 4;  // 4-aligned
                if (OUTMODE == 3) {
                    const int lcol = gcol - wsel * 768;
                    const int b  = t0 / SM_;
                    const int tt = t0 - b * SM_;
                    if (wsel == 0) {             // Q -> [B,1024,768] bf16
                        if (tt < S_) {
                            #pragma unroll
                            for (int r = 0; r < 4; ++r)
                                ((bf16*)Cout)[((size_t)b * S_ + tt + r) * D_ + lcol]
                                    = (bf16)(acc[i][j][r] + bv);
                        }
                    } else if (wsel == 1) {      // K -> [16640,768] bf16
                        #pragma unroll
                        for (int r = 0; r < 4; ++r)
                            ((bf16*)C2)[(size_t)(t0 + r) * D_ + lcol]
                                = (bf16)(acc[i][j][r] + bv);
                    } else {                     // V -> Vt[b, e, t] bf16x4
                        bf16x4 o;
                        #pragma unroll
                        for (int r = 0; r < 4; ++r) o[r] = (bf16)(acc[i][j][r] + bv);
                        *(bf16x4*)((bf16*)C3 +
                            ((size_t)b * D_ + lcol) * SMP_ + tt) = o;
                    }
                } else {
                    #pragma unroll
                    for (int r = 0; r < 4; ++r) {
                        const float val = acc[i][j][r] + bv;
                        const size_t idx = (size_t)z * sC
                                         + (size_t)(t0 + r) * ldc + gcol;
                        if (OUTMODE == 1) ((float*)Cout)[idx] = val;
                        else              ((bf16*)Cout)[idx]  = (bf16)val;
                    }
                }
            }
        }
    }
}

// ---------------------------------------------------------------------------
// Weight cast: wq/wk/wv -> one concatenated [2304,768] bf16 buffer, wo -> wob
// ---------------------------------------------------------------------------
__global__ void castw4_k(const float* __restrict__ w0, const float* __restrict__ w1,
                         const float* __restrict__ w2, const float* __restrict__ w3,
                         bf16* __restrict__ wqkv, bf16* __restrict__ wob)
{
    const float* in;
    bf16* out;
    const size_t NW = (size_t)D_ * D_;
    switch (blockIdx.y) {
        case 0: in = w0; out = wqkv;          break;
        case 1: in = w1; out = wqkv + NW;     break;
        case 2: in = w2; out = wqkv + 2 * NW; break;
        default: in = w3; out = wob;          break;
    }
    const int i = blockIdx.x * blockDim.x + threadIdx.x;   // float4 chunks
    const float4 f = ((const float4*)in)[i];
    bf16x4 v;
    v[0] = (bf16)f.x; v[1] = (bf16)f.y; v[2] = (bf16)f.z; v[3] = (bf16)f.w;
    ((bf16x4*)out)[i] = v;
}

// ---------------------------------------------------------------------------
// cstream[b*1040 + t][e] = bf16( t<1024 ? x[b,t,e] : mem[t-1024,e] )
// Last block (6240) instead concatenates bq|bk|bv into bqkv [2304] fp32.
// ---------------------------------------------------------------------------
__global__ void castx_k(const float* __restrict__ x, const float* __restrict__ mem,
                        bf16* __restrict__ cs,
                        const float* __restrict__ bq, const float* __restrict__ bk,
                        const float* __restrict__ bv, float* __restrict__ bqkv)
{
    if (blockIdx.x == 6240) {
        const int tid = threadIdx.x;
        if (tid < 576) {
            const int g = tid * 4;
            const float* src = (g < 768) ? (bq + g)
                             : (g < 1536) ? (bk + g - 768) : (bv + g - 1536);
            *(float4*)(bqkv + g) = *(const float4*)src;
        }
        return;
    }
    const int i = blockIdx.x * blockDim.x + threadIdx.x;  // 0 .. 16640*96-1
    const int row = i / 96;
    const int c8  = (i - row * 96) * 8;
    const int b   = row / SM_;
    const int tt  = row - b * SM_;
    const float* src = (tt < S_) ? (x + ((size_t)b * S_ + tt) * D_ + c8)
                                 : (mem + (size_t)(tt - S_) * D_ + c8);
    const float4 f0 = *(const float4*)src;
    const float4 f1 = *(const float4*)(src + 4);
    bf16x8 v;
    v[0] = (bf16)f0.x; v[1] = (bf16)f0.y; v[2] = (bf16)f0.z; v[3] = (bf16)f0.w;
    v[4] = (bf16)f1.x; v[5] = (bf16)f1.y; v[6] = (bf16)f1.z; v[7] = (bf16)f1.w;
    *(bf16x8*)(cs + (size_t)row * D_ + c8) = v;
}

// ---------------------------------------------------------------------------
// In-place softmax over P rows (bf16, stride 1088): reads raw scores,
// applies SCALE + mask, writes normalized probs; zero-fills pad cols.
// ---------------------------------------------------------------------------
__launch_bounds__(256)
__global__ void softmax_k(bf16* __restrict__ P, const float* __restrict__ mask)
{
    const int t   = threadIdx.x;
    const int row = blockIdx.x * 4 + (t >> 6);
    const int l   = t & 63;
    const int s   = row & 1023;
    bf16* prow = P + (size_t)row * SMP_;
    const float* mrow = mask + (size_t)s * SM_;

    float v[17];
    float m = -1e30f;
    #pragma unroll
    for (int it = 0; it < 17; ++it) {
        const int idx = l + it * 64;
        float x = -1e30f;
        if (idx < SM_) x = (float)prow[idx] * SCALE_ + mrow[idx];
        v[it] = x;
        m = fmaxf(m, x);
    }
    #pragma unroll
    for (int o = 32; o; o >>= 1) m = fmaxf(m, __shfl_xor(m, o));
    float sum = 0.f;
    #pragma unroll
    for (int it = 0; it < 17; ++it) {
        const int idx = l + it * 64;
        float e = 0.f;
        if (idx < SM_) e = __expf(v[it] - m);
        v[it] = e; sum += e;
    }
    #pragma unroll
    for (int o = 32; o; o >>= 1) sum += __shfl_xor(sum, o);
    const float inv = 1.f / sum;
    #pragma unroll
    for (int it = 0; it < 17; ++it) {
        const int idx = l + it * 64;
        if (idx < SMP_) prow[idx] = (bf16)(v[it] * inv);  // pad lanes write 0
    }
}

// ---------------------------------------------------------------------------
extern "C" void kernel_launch(void* const* d_in, const int* in_sizes, int n_in,
                              void* d_out, int out_size, void* d_ws, size_t ws_size,
                              hipStream_t stream) {
    const float* x    = (const float*)d_in[0];
    const float* mask = (const float*)d_in[1];
    const float* mem  = (const float*)d_in[2];
    const float* wq   = (const float*)d_in[3];
    const float* bq   = (const float*)d_in[4];
    const float* wk   = (const float*)d_in[5];
    const float* bk   = (const float*)d_in[6];
    const float* wv   = (const float*)d_in[7];
    const float* bv   = (const float*)d_in[8];
    const float* wo   = (const float*)d_in[9];
    const float* bo   = (const float*)d_in[10];

    bf16* w = (bf16*)d_ws;
    const size_t NW  = (size_t)D_ * D_;          //   589824
    const size_t NCS = (size_t)B_ * SM_ * D_;    // 12779520 (cstream / head_out)
    const size_t NQ  = (size_t)B_ * S_ * D_;     // 12582912
    const size_t NKV = (size_t)B_ * SM_ * D_;    // 12779520
    const size_t NVT = (size_t)B_ * D_ * SMP_;   // 13369344
    bf16* wqkv = w;                // [2304][768]
    bf16* wob  = wqkv + 3 * NW;
    bf16* cs   = wob + NW;         // concat(x, mem) bf16; reused as head_out
    bf16* qb   = cs  + NCS;
    bf16* kb   = qb  + NQ;
    bf16* vtb  = kb  + NKV;
    bf16* Pb   = vtb + NVT;        // [B,1024,1088] scores -> probs (in-place)
    float* bqkv = (float*)(Pb + (size_t)B_ * S_ * SMP_);  // [2304] fp32

    castw4_k<<<dim3(576, 4), 256, 0, stream>>>(wq, wk, wv, wo, wqkv, wob);
    castx_k<<<6241, 256, 0, stream>>>(x, mem, cs, bq, bk, bv, bqkv);

    // fused QKV: cs @ [wq;wk;wv]^T + bqkv -> qb / kb / vtb(transposed)
    gemm_k<3, 3><<<dim3(18, 130), 256, 0, stream>>>(
        cs, wqkv, bqkv, qb, kb, vtb, D_, D_, 0, D_, 3 * D_, 0, 0, 0);

    // raw scores = q @ k^T (XCD-swizzled; SCALE+mask applied in softmax)
    gemm_k<0, 1><<<1152, 256, 0, stream>>>(
        qb, kb, nullptr, Pb, nullptr, nullptr, D_, D_, SMP_, D_, SM_,
        (long)S_ * D_, (long)SM_ * D_, (long)S_ * SMP_);
    softmax_k<<<(B_ * S_) / 4, 256, 0, stream>>>(Pb, mask);

    // head_out = P @ V (XCD-swizzled; K=1088, pad contributes 0) -> cs reused
    gemm_k<0, 2><<<768, 256, 0, stream>>>(
        Pb, vtb, nullptr, cs, nullptr, nullptr, SMP_, SMP_, D_, SMP_, D_,
        (long)S_ * SMP_, (long)D_ * SMP_, (long)S_ * D_);

    // out = head_out @ wo^T + bo (fp32, col-tile-fast for A-tile L2 reuse)
    gemm_k<1, 3><<<dim3(6, 128), 256, 0, stream>>>(
        cs, wob, bo, d_out, nullptr, nullptr, D_, D_, D_, D_, D_, 0, 0, 0);
}